// Round 15
// baseline (245.979 us; speedup 1.0000x reference)
//
#include <hip/hip_runtime.h>
#include <hip/hip_bf16.h>
#include <math.h>

// ---------------- problem constants ----------------
#define BATCH   8
#define SEQL    8192
#define DOUTD   512
#define DHID    256
#define MTOT    (BATCH*SEQL)      // 65536
#define CHUNKS  128               // scan chunks per sequence
#define CHUNKLN 64                // SEQL/CHUNKS
#define SQUAR   6                 // log2(CHUNKLN)

typedef __bf16 bh;
typedef __bf16 bh8 __attribute__((ext_vector_type(8)));
typedef __bf16 bh2 __attribute__((ext_vector_type(2)));
typedef float  f32x4 __attribute__((ext_vector_type(4)));

// Hidden-state layout is INTERLEAVED: bu col 2n = re(unit n), col 2n+1 = im(unit n).
// Implemented purely as row permutations of wbt/bB/wct at prep time; GEMMs untouched.

// ---------------- setup: conv_x (16384) + W transpose (64) + prep0 (1) + bB (256) ----------------
__global__ void setup_kernel(const float4* __restrict__ x, bh* __restrict__ xh,
                             const float* __restrict__ W, float* __restrict__ Wt,
                             const float* __restrict__ nu_log, const float* __restrict__ theta_log,
                             const float* __restrict__ gamma_log, const float* __restrict__ Bre,
                             const float* __restrict__ Bim, const float* __restrict__ bvec,
                             const float* __restrict__ Dvec,
                             float* lamRe, float* lamIm, float* lamSRe, float* lamSIm,
                             float* gamma, float* bB, float* bD) {
    int bid = blockIdx.x;
    const int tid = threadIdx.x;
    if (bid < 16384) {                       // conv_x: fp32 -> bf16, 8 elems/thread
        long i = (long)bid * 256 + tid;
        float4 a = x[2 * i], c = x[2 * i + 1];
        bh8 o;
        o[0] = (bh)a.x; o[1] = (bh)a.y; o[2] = (bh)a.z; o[3] = (bh)a.w;
        o[4] = (bh)c.x; o[5] = (bh)c.y; o[6] = (bh)c.z; o[7] = (bh)c.w;
        *(bh8*)(xh + i * 8) = o;
        return;
    }
    bid -= 16384;
    if (bid < 64) {                          // W transpose, 64x64 LDS tiles
        __shared__ float t[64][65];
        const int bx = bid & 7, by = bid >> 3;
        const int r0 = by * 64, c0 = bx * 64;
        const int tr = tid >> 4;
        const int tc = (tid & 15) * 4;
#pragma unroll
        for (int rr = 0; rr < 64; rr += 16) {
            float4 v = *(const float4*)&W[(size_t)(r0 + tr + rr) * 512 + c0 + tc];
            t[tr + rr][tc + 0] = v.x; t[tr + rr][tc + 1] = v.y;
            t[tr + rr][tc + 2] = v.z; t[tr + rr][tc + 3] = v.w;
        }
        __syncthreads();
#pragma unroll
        for (int rr = 0; rr < 64; rr += 16) {
            const int orow = tr + rr;
            float4 o;
            o.x = t[tc + 0][orow]; o.y = t[tc + 1][orow];
            o.z = t[tc + 2][orow]; o.w = t[tc + 3][orow];
            *(float4*)&Wt[(size_t)(c0 + orow) * 512 + r0 + tc] = o;
        }
        return;
    }
    bid -= 64;
    if (bid == 0) {                          // prep0: lam, lam^S, gamma, bD (cheap)
        for (int t = tid; t < 512; t += 256) bD[t] = bvec[t] * Dvec[t];
        int t = tid;
        if (t < 256) {
            float nu = expf(nu_log[t]);
            float th = expf(theta_log[t]);
            float mag = expf(-nu);
            float lr = mag * cosf(th), li = mag * sinf(th);
            lamRe[t] = lr; lamIm[t] = li;
            float pr = lr, pi = li;
            for (int s = 0; s < SQUAR; ++s) { float nr = pr*pr - pi*pi, ni = 2.f*pr*pi; pr = nr; pi = ni; }
            lamSRe[t] = pr; lamSIm[t] = pi;
            gamma[t] = expf(gamma_log[t]);
        }
        return;
    }
    // bB blocks: one per hidden unit t, coalesced matvec + LDS reduce
    const int t = bid - 1;                   // 0..255
    __shared__ float rr[256], ri[256];
    float b0 = bvec[tid], b1 = bvec[tid + 256];
    float pr = b0 * Bre[(size_t)t * 512 + tid] + b1 * Bre[(size_t)t * 512 + tid + 256];
    float pi = b0 * Bim[(size_t)t * 512 + tid] + b1 * Bim[(size_t)t * 512 + tid + 256];
    rr[tid] = pr; ri[tid] = pi;
    __syncthreads();
    for (int s = 128; s > 0; s >>= 1) {
        if (tid < s) { rr[tid] += rr[tid + s]; ri[tid] += ri[tid + s]; }
        __syncthreads();
    }
    if (tid == 0) {
        float g = expf(gamma_log[t]);
        bB[2 * t]     = rr[0] * g;           // interleaved bias
        bB[2 * t + 1] = ri[0] * g;
    }
}

// ---------------- prepBC: prepWB (128 blocks) + prepWC (2048 blocks) ----------------
__global__ void prepBC_kernel(const float* __restrict__ Wt, const float* __restrict__ Bre,
                              const float* __restrict__ Bim, const float* __restrict__ gamma,
                              bh* __restrict__ WBt,
                              const float* __restrict__ Cre, const float* __restrict__ Cim,
                              const float* __restrict__ Dvec, bh* __restrict__ WcT) {
    if (blockIdx.x < 128) {
        __shared__ float bsh[4][512];
        const int c0 = blockIdx.x * 4;
        const int tid = threadIdx.x;
        for (int i = tid; i < 2048; i += 256) {
            int ci = i >> 9, k = i & 511;
            int c = c0 + ci;
            float v = (c < 256) ? Bre[(size_t)c * 512 + k] : Bim[(size_t)(c - 256) * 512 + k];
            bsh[ci][k] = v * gamma[c & 255];
        }
        __syncthreads();
        const int j = tid * 2;
        float a0[4] = {}, a1[4] = {};
        for (int k = 0; k < 512; ++k) {
            float2 wv = *(const float2*)&Wt[(size_t)k * 512 + j];
#pragma unroll
            for (int ci = 0; ci < 4; ++ci) {
                float b = bsh[ci][k];
                a0[ci] += wv.x * b;
                a1[ci] += wv.y * b;
            }
        }
#pragma unroll
        for (int ci = 0; ci < 4; ++ci) {
            const int c = c0 + ci;
            const int r = (c < 256) ? 2 * c : 2 * (c - 256) + 1;   // interleave map
            WBt[(size_t)r * 512 + j]     = (bh)a0[ci];
            WBt[(size_t)r * 512 + j + 1] = (bh)a1[ci];
        }
        return;
    }
    // prepWC: k'<512 interleaved h dims: even->Cre[n], odd->-Cim[n]; else Wt*D
    int e = (blockIdx.x - 128) * 256 + threadIdx.x;   // over 512*1024
    int c = e >> 10, kp = e & 1023;
    float v;
    if (kp < 512) {
        int n = kp >> 1;
        v = (kp & 1) ? -Cim[c * 256 + n] : Cre[c * 256 + n];
    } else {
        v = Wt[(size_t)c * 512 + (kp - 512)] * Dvec[c];
    }
    WcT[e] = (bh)v;
}

// ---------------- shared GEMM macros ----------------
#define MMAQ(mh, nh) \
  _Pragma("unroll") for (int ks = 0; ks < 2; ++ks) \
  _Pragma("unroll") for (int mi = 0; mi < 4; ++mi) \
  _Pragma("unroll") for (int ni = 0; ni < 2; ++ni) \
    acc[(mh)*4+mi][(nh)*2+ni] = __builtin_amdgcn_mfma_f32_16x16x32_bf16( \
        afr[mi*2+ks], bfr[ni*2+ks], acc[(mh)*4+mi][(nh)*2+ni], 0, 0, 0);

#define PH_MMA(mh, nh) \
  __builtin_amdgcn_s_barrier(); \
  __builtin_amdgcn_s_setprio(1); \
  MMAQ(mh, nh) \
  __builtin_amdgcn_s_setprio(0); \
  __builtin_amdgcn_s_barrier();

// ============ gemm: 256x256 tile, BK=64, 8-phase ============
// r15 change: EARLY burst staging — tile t1 staged entirely at ph1(A)+ph2(B),
// tile t0+2 at ph5(A)+ph6(B); closes wait vmcnt(0) on loads issued 2-3 phases
// earlier (~700-1000cy cover vs r14's 1-1.5 phases -> ~500cy stall per close).
template<int KTOT, bool SPLIT_A, bool OUT_F32>
__global__ __launch_bounds__(512, 2)
void gemm_kernel(const bh* __restrict__ A0, const bh* __restrict__ A1,
                 const bh* __restrict__ Bw, const float* __restrict__ bias,
                 float* __restrict__ outF, bh* __restrict__ outH) {
    __shared__ alignas(16) bh lds[65536];
    const int tid = threadIdx.x;
    const int l = tid & 63, w = tid >> 6;
    const int wm = w >> 2, wn = w & 3;
    const int bid = blockIdx.x, nwg = gridDim.x;
    const int swz = (bid & 7) * (nwg >> 3) + (bid >> 3);
    const int rowBase = (swz >> 1) * 256;
    const int colBase = (swz & 1) * 256;
    const int rsub = l & 15, g = l >> 4;
    const int r7 = rsub & 7;
    const int sl0 = ((0 + g) ^ r7) * 8;
    const int sl1 = ((4 + g) ^ r7) * 8;
    const int st_r  = tid >> 3;
    const int st_sl = ((tid & 7) ^ (st_r & 7)) * 8;
    const int st_ld = (tid & 7) * 8;

    f32x4 acc[8][4] = {};
    bh8 afr[8];
    bh8 bfr[4];

    const int NT  = KTOT / 64;
    const int NIT = NT / 2;

    auto stageA = [&](int t, int half, int bufsel) {
        const int k0 = t * 64;
        const bh* As = A0; int kk = k0;
        if (SPLIT_A && k0 >= 512) { As = A1; kk = k0 - 512; }
        bh* lb = &lds[bufsel * 32768];
#pragma unroll
        for (int j = 0; j < 2; ++j) {
            const int rt = half * 128 + j * 64 + st_r;
            const bh* ga = As + (size_t)(rowBase + rt) * 512 + kk + st_sl;
            __builtin_amdgcn_global_load_lds(
                (const __attribute__((address_space(1))) void*)ga,
                (__attribute__((address_space(3))) void*)&lb[rt * 64 + st_ld], 16, 0, 0);
        }
    };
    auto stageB = [&](int t, int half, int bufsel) {
        const int k0 = t * 64;
        bh* lb = &lds[bufsel * 32768 + 16384];
#pragma unroll
        for (int j = 0; j < 2; ++j) {
            const int rt = half * 128 + j * 64 + st_r;
            const bh* gb = Bw + (size_t)(colBase + rt) * KTOT + k0 + st_sl;
            __builtin_amdgcn_global_load_lds(
                (const __attribute__((address_space(1))) void*)gb,
                (__attribute__((address_space(3))) void*)&lb[rt * 64 + st_ld], 16, 0, 0);
        }
    };
    auto dsA = [&](int mh, int bufsel) {
        const bh* lb = &lds[bufsel * 32768];
#pragma unroll
        for (int mi = 0; mi < 4; ++mi) {
            const int row = wm * 128 + (mh * 4 + mi) * 16 + rsub;
            afr[mi * 2 + 0] = *(const bh8*)&lb[row * 64 + sl0];
            afr[mi * 2 + 1] = *(const bh8*)&lb[row * 64 + sl1];
        }
    };
    auto dsB = [&](int nh, int bufsel) {
        const bh* lb = &lds[bufsel * 32768 + 16384];
#pragma unroll
        for (int ni = 0; ni < 2; ++ni) {
            const int row = wn * 64 + (nh * 2 + ni) * 16 + rsub;
            bfr[ni * 2 + 0] = *(const bh8*)&lb[row * 64 + sl0];
            bfr[ni * 2 + 1] = *(const bh8*)&lb[row * 64 + sl1];
        }
    };

    // prologue: tile 0 fully staged, drain, go
    stageA(0, 0, 0); stageA(0, 1, 0); stageB(0, 0, 0); stageB(0, 1, 0);
    asm volatile("s_waitcnt vmcnt(0)" ::: "memory");
    __builtin_amdgcn_sched_barrier(0);
    __builtin_amdgcn_s_barrier();

    for (int i = 0; i < NIT; ++i) {
        const int t0 = 2 * i, t1 = 2 * i + 1;
        // ph1 [buf0]: Q(0,0); stage ALL of A(t1)->buf1
        dsA(0, 0); dsB(0, 0);
        stageA(t1, 0, 1); stageA(t1, 1, 1);
        PH_MMA(0, 0)
        // ph2: Q(0,1); stage ALL of B(t1)->buf1
        dsB(1, 0);
        stageB(t1, 0, 1); stageB(t1, 1, 1);
        PH_MMA(0, 1)
        // ph3: Q(1,1); no staging (t1's loads aging)
        dsA(1, 0);
        PH_MMA(1, 1)
        // ph4: Q(1,0); close: drain t1 (issued 2-3 phases ago)
        dsB(0, 0);
        __builtin_amdgcn_s_barrier();
        __builtin_amdgcn_s_setprio(1);
        MMAQ(1, 0)
        __builtin_amdgcn_s_setprio(0);
        asm volatile("s_waitcnt vmcnt(0)" ::: "memory");
        __builtin_amdgcn_sched_barrier(0);
        __builtin_amdgcn_s_barrier();
        // ph5 [buf1]: Q(0,0); stage ALL of A(t0+2)->buf0
        dsA(0, 1); dsB(0, 1);
        if (t0 + 2 < NT) { stageA(t0 + 2, 0, 0); stageA(t0 + 2, 1, 0); }
        PH_MMA(0, 0)
        // ph6: Q(0,1); stage ALL of B(t0+2)->buf0
        dsB(1, 1);
        if (t0 + 2 < NT) { stageB(t0 + 2, 0, 0); stageB(t0 + 2, 1, 0); }
        PH_MMA(0, 1)
        // ph7: Q(1,1)
        dsA(1, 1);
        PH_MMA(1, 1)
        // ph8: Q(1,0); close: drain t0+2
        dsB(0, 1);
        __builtin_amdgcn_s_barrier();
        __builtin_amdgcn_s_setprio(1);
        MMAQ(1, 0)
        __builtin_amdgcn_s_setprio(0);
        asm volatile("s_waitcnt vmcnt(0)" ::: "memory");
        __builtin_amdgcn_sched_barrier(0);
        __builtin_amdgcn_s_barrier();
    }

#pragma unroll
    for (int m = 0; m < 8; ++m)
#pragma unroll
        for (int j = 0; j < 4; ++j) {
            const int row = rowBase + wm * 128 + m * 16 + g * 4 + j;
#pragma unroll
            for (int n = 0; n < 4; ++n) {
                const int col = colBase + wn * 64 + n * 16 + rsub;
                float v = acc[m][n][j] + bias[col];
                if (OUT_F32) outF[(size_t)row * 512 + col] = v;
                else         outH[(size_t)row * 512 + col] = (bh)v;
            }
        }
}

// ---------------- chunked complex scan (3 passes), interleaved 4B loads ----------------
__global__ void scan1_kernel(const bh* __restrict__ Bu, const float* __restrict__ lamRe,
                             const float* __restrict__ lamIm, float* __restrict__ carRe,
                             float* __restrict__ carIm) {
    int b = blockIdx.x >> 7, c = blockIdx.x & (CHUNKS - 1);
    int n = threadIdx.x;
    float lr = lamRe[n], li = lamIm[n];
    float hr = 0.f, hi = 0.f;
    const unsigned* p = (const unsigned*)Bu + ((size_t)(b * SEQL + c * CHUNKLN)) * 256 + n;
    for (int i = 0; i < CHUNKLN; ++i) {
        unsigned u = *p;
        float br = __uint_as_float(u << 16);
        float bi = __uint_as_float(u & 0xffff0000u);
        float nr = lr * hr - li * hi + br;
        float ni = lr * hi + li * hr + bi;
        hr = nr; hi = ni; p += 256;
    }
    carRe[(size_t)blockIdx.x * 256 + n] = hr;
    carIm[(size_t)blockIdx.x * 256 + n] = hi;
}

__global__ void scan2_kernel(const float* __restrict__ carRe, const float* __restrict__ carIm,
                             const float* __restrict__ lamSRe, const float* __restrict__ lamSIm,
                             float* __restrict__ iniRe, float* __restrict__ iniIm) {
    int b = blockIdx.x, n = threadIdx.x;
    float lr = lamSRe[n], li = lamSIm[n];
    float hr = 0.f, hi = 0.f;
    for (int c = 0; c < CHUNKS; ++c) {
        size_t idx = ((size_t)b * CHUNKS + c) * 256 + n;
        iniRe[idx] = hr; iniIm[idx] = hi;
        float cr = carRe[idx], ci = carIm[idx];
        float nr = lr * hr - li * hi + cr;
        float ni = lr * hi + li * hr + ci;
        hr = nr; hi = ni;
    }
}

__global__ void scan3_kernel(bh* __restrict__ Bu, const float* __restrict__ lamRe,
                             const float* __restrict__ lamIm, const float* __restrict__ iniRe,
                             const float* __restrict__ iniIm, float* __restrict__ outTail,
                             int tailN) {
    int b = blockIdx.x >> 7, c = blockIdx.x & (CHUNKS - 1);
    int n = threadIdx.x;
    float lr = lamRe[n], li = lamIm[n];
    size_t idx = (size_t)blockIdx.x * 256 + n;
    float hr = iniRe[idx], hi = iniIm[idx];
    unsigned* p = (unsigned*)Bu + ((size_t)(b * SEQL + c * CHUNKLN)) * 256 + n;
    for (int i = 0; i < CHUNKLN; ++i) {
        unsigned u = *p;
        float br = __uint_as_float(u << 16);
        float bi = __uint_as_float(u & 0xffff0000u);
        float nr = lr * hr - li * hi + br;
        float ni = lr * hi + li * hr + bi;
        hr = nr; hi = ni;
        bh2 o; o[0] = (bh)hr; o[1] = (bh)hi;
        *(bh2*)p = o;
        p += 256;
    }
    if (c == CHUNKS - 1) {
        if (tailN >= 4096) {
            outTail[b * 256 + n]        = hr;
            outTail[2048 + b * 256 + n] = hi;
        } else {
            outTail[b * 256 + n] = hr;
        }
    }
}

// ---------------- launch ----------------
extern "C" void kernel_launch(void* const* d_in, const int* in_sizes, int n_in,
                              void* d_out, int out_size, void* d_ws, size_t ws_size,
                              hipStream_t stream) {
    const float* x        = (const float*)d_in[0];
    const float* W        = (const float*)d_in[1];
    const float* bvec     = (const float*)d_in[2];
    const float* nu_log   = (const float*)d_in[3];
    const float* theta_lg = (const float*)d_in[4];
    const float* gamma_lg = (const float*)d_in[5];
    const float* Bre      = (const float*)d_in[6];
    const float* Bim      = (const float*)d_in[7];
    const float* Cre      = (const float*)d_in[8];
    const float* Cim      = (const float*)d_in[9];
    const float* Dvec     = (const float*)d_in[10];

    char* ws = (char*)d_ws;
    bh* xh   = (bh*)(ws);                                   // 64 MB
    bh* bu   = (bh*)(ws + 67108864);                        // 64 MB (becomes h in-place)
    bh* wbt  = (bh*)(ws + 134217728);                       // 512 KB
    bh* wct  = (bh*)(ws + 134217728 + 524288);              // 1 MB
    float* Wt = (float*)(ws + 134217728 + 524288 + 1048576); // 1 MB
    float* sm = (float*)(ws + 134217728 + 524288 + 1048576 + 1048576);
    float* bB = sm;               // 512 (interleaved)
    float* bD = sm + 512;         // 512
    float* lamRe  = sm + 1024;    // 256
    float* lamIm  = sm + 1280;
    float* lamSRe = sm + 1536;
    float* lamSIm = sm + 1792;
    float* gamma  = sm + 2048;    // 256
    float* carRe  = sm + 2304;                 // 8*128*256 each
    float* carIm  = carRe + (size_t)BATCH * CHUNKS * 256;
    float* iniRe  = carIm + (size_t)BATCH * CHUNKS * 256;
    float* iniIm  = iniRe + (size_t)BATCH * CHUNKS * 256;

    float* outF    = (float*)d_out;
    float* outTail = outF + (size_t)MTOT * DOUTD;
    int tailN = out_size - MTOT * DOUTD;       // 4096 (float view) or 2048

    setup_kernel<<<16705, 256, 0, stream>>>((const float4*)x, xh, W, Wt,
                                            nu_log, theta_lg, gamma_lg, Bre, Bim, bvec, Dvec,
                                            lamRe, lamIm, lamSRe, lamSIm, gamma, bB, bD);
    prepBC_kernel<<<2176, 256, 0, stream>>>(Wt, Bre, Bim, gamma, wbt, Cre, Cim, Dvec, wct);

    gemm_kernel<512, false, false><<<512, 512, 0, stream>>>(xh, nullptr, wbt, bB, nullptr, bu);

    scan1_kernel<<<BATCH * CHUNKS, 256, 0, stream>>>(bu, lamRe, lamIm, carRe, carIm);
    scan2_kernel<<<BATCH, 256, 0, stream>>>(carRe, carIm, lamSRe, lamSIm, iniRe, iniIm);
    scan3_kernel<<<BATCH * CHUNKS, 256, 0, stream>>>(bu, lamRe, lamIm, iniRe, iniIm, outTail, tailN);

    gemm_kernel<1024, true, true><<<512, 512, 0, stream>>>(bu, xh, wct, bD, outF, nullptr);
}

// Round 16
// 238.423 us; speedup vs baseline: 1.0317x; 1.0317x over previous
//
#include <hip/hip_runtime.h>
#include <hip/hip_bf16.h>
#include <math.h>

// ---------------- problem constants ----------------
#define BATCH   8
#define SEQL    8192
#define DOUTD   512
#define DHID    256
#define MTOT    (BATCH*SEQL)      // 65536
#define CHUNKS  128               // scan chunks per sequence
#define CHUNKLN 64                // SEQL/CHUNKS
#define SQUAR   6                 // log2(CHUNKLN)

typedef __bf16 bh;
typedef __bf16 bh8 __attribute__((ext_vector_type(8)));
typedef __bf16 bh2 __attribute__((ext_vector_type(2)));
typedef float  f32x4 __attribute__((ext_vector_type(4)));

// Hidden-state layout is INTERLEAVED: bu col 2n = re(unit n), col 2n+1 = im(unit n).

// ---------------- setup: conv_x (16384) + W transpose (64) + prep0 (1) + bB (256) ----------------
__global__ void setup_kernel(const float4* __restrict__ x, bh* __restrict__ xh,
                             const float* __restrict__ W, float* __restrict__ Wt,
                             const float* __restrict__ nu_log, const float* __restrict__ theta_log,
                             const float* __restrict__ gamma_log, const float* __restrict__ Bre,
                             const float* __restrict__ Bim, const float* __restrict__ bvec,
                             const float* __restrict__ Dvec,
                             float* lamRe, float* lamIm, float* lamSRe, float* lamSIm,
                             float* gamma, float* bB, float* bD) {
    int bid = blockIdx.x;
    const int tid = threadIdx.x;
    if (bid < 16384) {                       // conv_x: fp32 -> bf16, 8 elems/thread
        long i = (long)bid * 256 + tid;
        float4 a = x[2 * i], c = x[2 * i + 1];
        bh8 o;
        o[0] = (bh)a.x; o[1] = (bh)a.y; o[2] = (bh)a.z; o[3] = (bh)a.w;
        o[4] = (bh)c.x; o[5] = (bh)c.y; o[6] = (bh)c.z; o[7] = (bh)c.w;
        *(bh8*)(xh + i * 8) = o;
        return;
    }
    bid -= 16384;
    if (bid < 64) {                          // W transpose, 64x64 LDS tiles
        __shared__ float t[64][65];
        const int bx = bid & 7, by = bid >> 3;
        const int r0 = by * 64, c0 = bx * 64;
        const int tr = tid >> 4;
        const int tc = (tid & 15) * 4;
#pragma unroll
        for (int rr = 0; rr < 64; rr += 16) {
            float4 v = *(const float4*)&W[(size_t)(r0 + tr + rr) * 512 + c0 + tc];
            t[tr + rr][tc + 0] = v.x; t[tr + rr][tc + 1] = v.y;
            t[tr + rr][tc + 2] = v.z; t[tr + rr][tc + 3] = v.w;
        }
        __syncthreads();
#pragma unroll
        for (int rr = 0; rr < 64; rr += 16) {
            const int orow = tr + rr;
            float4 o;
            o.x = t[tc + 0][orow]; o.y = t[tc + 1][orow];
            o.z = t[tc + 2][orow]; o.w = t[tc + 3][orow];
            *(float4*)&Wt[(size_t)(c0 + orow) * 512 + r0 + tc] = o;
        }
        return;
    }
    bid -= 64;
    if (bid == 0) {                          // prep0: lam, lam^S, gamma, bD (cheap)
        for (int t = tid; t < 512; t += 256) bD[t] = bvec[t] * Dvec[t];
        int t = tid;
        if (t < 256) {
            float nu = expf(nu_log[t]);
            float th = expf(theta_log[t]);
            float mag = expf(-nu);
            float lr = mag * cosf(th), li = mag * sinf(th);
            lamRe[t] = lr; lamIm[t] = li;
            float pr = lr, pi = li;
            for (int s = 0; s < SQUAR; ++s) { float nr = pr*pr - pi*pi, ni = 2.f*pr*pi; pr = nr; pi = ni; }
            lamSRe[t] = pr; lamSIm[t] = pi;
            gamma[t] = expf(gamma_log[t]);
        }
        return;
    }
    // bB blocks: one per hidden unit t, coalesced matvec + LDS reduce
    const int t = bid - 1;                   // 0..255
    __shared__ float rr[256], ri[256];
    float b0 = bvec[tid], b1 = bvec[tid + 256];
    float pr = b0 * Bre[(size_t)t * 512 + tid] + b1 * Bre[(size_t)t * 512 + tid + 256];
    float pi = b0 * Bim[(size_t)t * 512 + tid] + b1 * Bim[(size_t)t * 512 + tid + 256];
    rr[tid] = pr; ri[tid] = pi;
    __syncthreads();
    for (int s = 128; s > 0; s >>= 1) {
        if (tid < s) { rr[tid] += rr[tid + s]; ri[tid] += ri[tid + s]; }
        __syncthreads();
    }
    if (tid == 0) {
        float g = expf(gamma_log[t]);
        bB[2 * t]     = rr[0] * g;           // interleaved bias
        bB[2 * t + 1] = ri[0] * g;
    }
}

// ---------------- prepBC: prepWB (128 blocks) + prepWC (2048 blocks) ----------------
__global__ void prepBC_kernel(const float* __restrict__ Wt, const float* __restrict__ Bre,
                              const float* __restrict__ Bim, const float* __restrict__ gamma,
                              bh* __restrict__ WBt,
                              const float* __restrict__ Cre, const float* __restrict__ Cim,
                              const float* __restrict__ Dvec, bh* __restrict__ WcT) {
    if (blockIdx.x < 128) {
        __shared__ float bsh[4][512];
        const int c0 = blockIdx.x * 4;
        const int tid = threadIdx.x;
        for (int i = tid; i < 2048; i += 256) {
            int ci = i >> 9, k = i & 511;
            int c = c0 + ci;
            float v = (c < 256) ? Bre[(size_t)c * 512 + k] : Bim[(size_t)(c - 256) * 512 + k];
            bsh[ci][k] = v * gamma[c & 255];
        }
        __syncthreads();
        const int j = tid * 2;
        float a0[4] = {}, a1[4] = {};
        for (int k = 0; k < 512; ++k) {
            float2 wv = *(const float2*)&Wt[(size_t)k * 512 + j];
#pragma unroll
            for (int ci = 0; ci < 4; ++ci) {
                float b = bsh[ci][k];
                a0[ci] += wv.x * b;
                a1[ci] += wv.y * b;
            }
        }
#pragma unroll
        for (int ci = 0; ci < 4; ++ci) {
            const int c = c0 + ci;
            const int r = (c < 256) ? 2 * c : 2 * (c - 256) + 1;   // interleave map
            WBt[(size_t)r * 512 + j]     = (bh)a0[ci];
            WBt[(size_t)r * 512 + j + 1] = (bh)a1[ci];
        }
        return;
    }
    // prepWC: k'<512 interleaved h dims: even->Cre[n], odd->-Cim[n]; else Wt*D
    int e = (blockIdx.x - 128) * 256 + threadIdx.x;   // over 512*1024
    int c = e >> 10, kp = e & 1023;
    float v;
    if (kp < 512) {
        int n = kp >> 1;
        v = (kp & 1) ? -Cim[c * 256 + n] : Cre[c * 256 + n];
    } else {
        v = Wt[(size_t)c * 512 + (kp - 512)] * Dvec[c];
    }
    WcT[e] = (bh)v;
}

// ---------------- shared GEMM macros ----------------
#define MMAQ(mh, nh) \
  _Pragma("unroll") for (int ks = 0; ks < 2; ++ks) \
  _Pragma("unroll") for (int mi = 0; mi < 4; ++mi) \
  _Pragma("unroll") for (int ni = 0; ni < 2; ++ni) \
    acc[(mh)*4+mi][(nh)*2+ni] = __builtin_amdgcn_mfma_f32_16x16x32_bf16( \
        afr[mi*2+ks], bfr[ni*2+ks], acc[(mh)*4+mi][(nh)*2+ni], 0, 0, 0);

#define PH_MMA(mh, nh) \
  __builtin_amdgcn_s_barrier(); \
  __builtin_amdgcn_s_setprio(1); \
  MMAQ(mh, nh) \
  __builtin_amdgcn_s_setprio(0); \
  __builtin_amdgcn_s_barrier();

// ============ gemm: 256x256 tile, BK=64, 8-phase, half-tile prefetch ring ============
// r16: m201-style counted-vmcnt protocol. LDS per buffer: A[mh][wm][64][64],
// B[nh][wn][32][64] sub-blocks so each half-tile {A0,A1,B0,B1} has ONE last-reader
// phase. Stage 1 half-tile per phase in consumption order; 3 half-tiles (6 loads)
// stay in flight across the ph4/ph8 closes -> vmcnt(6), never 0 in steady state.
// Half lifetimes (buf0): A0@ph1, B1@ph2, A1@ph3, B0@ph1..4 -> stages at
// ph2(A0) ph3(B1) ph4(A1) ph5(B0) legal after last reader's trailing barrier.
template<int KTOT, bool SPLIT_A, bool OUT_F32>
__global__ __launch_bounds__(512, 2)
void gemm_kernel(const bh* __restrict__ A0v, const bh* __restrict__ A1v,
                 const bh* __restrict__ Bw, const float* __restrict__ bias,
                 float* __restrict__ outF, bh* __restrict__ outH) {
    __shared__ alignas(16) bh lds[65536];
    const int tid = threadIdx.x;
    const int l = tid & 63, w = tid >> 6;
    const int wm = w >> 2, wn = w & 3;
    const int bid = blockIdx.x, nwg = gridDim.x;
    const int swz = (bid & 7) * (nwg >> 3) + (bid >> 3);
    const int rowBase = (swz >> 1) * 256;
    const int colBase = (swz & 1) * 256;
    const int rsub = l & 15, g = l >> 4;
    const int r7 = rsub & 7;
    const int sl0 = ((0 + g) ^ r7) * 8;
    const int sl1 = ((4 + g) ^ r7) * 8;
    const int strl = tid >> 3;                      // stage row-local 0..63
    const int stsl = ((tid & 7) ^ (strl & 7)) * 8;  // swizzled global col offset

    f32x4 acc[8][4] = {};
    bh8 afr[8];
    bh8 bfr[4];

    const int NT  = KTOT / 64;
    const int NIT = NT / 2;

    auto stageA = [&](int t, int mh, int bufsel) {   // half mh -> 2 gloads
        const int k0 = t * 64;
        const bh* As = A0v; int kk = k0;
        if (SPLIT_A && k0 >= 512) { As = A1v; kk = k0 - 512; }
        bh* lb = &lds[bufsel * 32768 + mh * 8192];
#pragma unroll
        for (int j = 0; j < 2; ++j) {
            const int gr = j * 128 + mh * 64 + strl;
            const bh* ga = As + (size_t)(rowBase + gr) * 512 + kk + stsl;
            __builtin_amdgcn_global_load_lds(
                (const __attribute__((address_space(1))) void*)ga,
                (__attribute__((address_space(3))) void*)&lb[j * 4096 + tid * 8], 16, 0, 0);
        }
    };
    auto stageB = [&](int t, int nh, int bufsel) {   // half nh -> 2 gloads
        const int k0 = t * 64;
        bh* lb = &lds[bufsel * 32768 + 16384 + nh * 8192];
#pragma unroll
        for (int j = 0; j < 2; ++j) {
            const int wnj = j * 2 + (strl >> 5);
            const int gr = wnj * 64 + nh * 32 + (strl & 31);
            const bh* gb = Bw + (size_t)(colBase + gr) * KTOT + k0 + stsl;
            __builtin_amdgcn_global_load_lds(
                (const __attribute__((address_space(1))) void*)gb,
                (__attribute__((address_space(3))) void*)&lb[j * 4096 + tid * 8], 16, 0, 0);
        }
    };
    auto dsA = [&](int mh, int bufsel) {
        const bh* lb = &lds[bufsel * 32768 + mh * 8192 + wm * 4096];
#pragma unroll
        for (int mi = 0; mi < 4; ++mi) {
            const int ro = (mi * 16 + rsub) * 64;
            afr[mi * 2 + 0] = *(const bh8*)&lb[ro + sl0];
            afr[mi * 2 + 1] = *(const bh8*)&lb[ro + sl1];
        }
    };
    auto dsB = [&](int nh, int bufsel) {
        const bh* lb = &lds[bufsel * 32768 + 16384 + nh * 8192 + wn * 2048];
#pragma unroll
        for (int ni = 0; ni < 2; ++ni) {
            const int ro = (ni * 16 + rsub) * 64;
            bfr[ni * 2 + 0] = *(const bh8*)&lb[ro + sl0];
            bfr[ni * 2 + 1] = *(const bh8*)&lb[ro + sl1];
        }
    };

    // prologue: tile0 complete (8 loads) + t1's A0,B1,A1 (6 loads); keep 6 in flight
    stageA(0, 0, 0); stageB(0, 0, 0); stageB(0, 1, 0); stageA(0, 1, 0);
    stageA(1, 0, 1); stageB(1, 1, 1); stageA(1, 1, 1);
    asm volatile("s_waitcnt vmcnt(6)" ::: "memory");
    __builtin_amdgcn_sched_barrier(0);
    __builtin_amdgcn_s_barrier();

    for (int i = 0; i < NIT; ++i) {
        const int t0 = 2 * i, t1 = 2 * i + 1;
        const bool p2 = (t0 + 2 < NT);
        const bool p3 = (t1 + 2 < NT);
        // ph1 [buf0]: Q(0,0); stage B0(t1)->buf1 (read at ph5)
        dsA(0, 0); dsB(0, 0);
        stageB(t1, 0, 1);
        PH_MMA(0, 0)
        // ph2: Q(0,1); stage A0(t0+2)->buf0 (A0 buf0 last read ph1)
        dsB(1, 0);
        if (p2) stageA(t0 + 2, 0, 0);
        PH_MMA(0, 1)
        // ph3: Q(1,1); stage B1(t0+2)->buf0 (B1 buf0 last read ph2)
        dsA(1, 0);
        if (p2) stageB(t0 + 2, 1, 0);
        PH_MMA(1, 1)
        // ph4: Q(1,0); stage A1(t0+2)->buf0 (A1 buf0 last read ph3); close vmcnt(6)
        dsB(0, 0);
        if (p2) stageA(t0 + 2, 1, 0);
        __builtin_amdgcn_s_barrier();
        __builtin_amdgcn_s_setprio(1);
        MMAQ(1, 0)
        __builtin_amdgcn_s_setprio(0);
        if (p2) { asm volatile("s_waitcnt vmcnt(6)" ::: "memory"); }   // B0(t1) landed
        else    { asm volatile("s_waitcnt vmcnt(0)" ::: "memory"); }
        __builtin_amdgcn_sched_barrier(0);
        __builtin_amdgcn_s_barrier();
        // ph5 [buf1]: Q(0,0); stage B0(t0+2)->buf0 (B0 buf0 last read ph4)
        dsA(0, 1); dsB(0, 1);
        if (p2) stageB(t0 + 2, 0, 0);
        PH_MMA(0, 0)
        // ph6: Q(0,1); stage A0(t1+2)->buf1
        dsB(1, 1);
        if (p3) stageA(t1 + 2, 0, 1);
        PH_MMA(0, 1)
        // ph7: Q(1,1); stage B1(t1+2)->buf1
        dsA(1, 1);
        if (p3) stageB(t1 + 2, 1, 1);
        PH_MMA(1, 1)
        // ph8: Q(1,0); stage A1(t1+2)->buf1; close vmcnt(6)
        dsB(0, 1);
        if (p3) stageA(t1 + 2, 1, 1);
        __builtin_amdgcn_s_barrier();
        __builtin_amdgcn_s_setprio(1);
        MMAQ(1, 0)
        __builtin_amdgcn_s_setprio(0);
        if (p3) { asm volatile("s_waitcnt vmcnt(6)" ::: "memory"); }   // B0(t0+2) landed
        else    { asm volatile("s_waitcnt vmcnt(0)" ::: "memory"); }
        __builtin_amdgcn_sched_barrier(0);
        __builtin_amdgcn_s_barrier();
    }

#pragma unroll
    for (int m = 0; m < 8; ++m)
#pragma unroll
        for (int j = 0; j < 4; ++j) {
            const int row = rowBase + wm * 128 + m * 16 + g * 4 + j;
#pragma unroll
            for (int n = 0; n < 4; ++n) {
                const int col = colBase + wn * 64 + n * 16 + rsub;
                float v = acc[m][n][j] + bias[col];
                if (OUT_F32) outF[(size_t)row * 512 + col] = v;
                else         outH[(size_t)row * 512 + col] = (bh)v;
            }
        }
}

// ---------------- chunked complex scan (3 passes), interleaved 4B loads ----------------
__global__ void scan1_kernel(const bh* __restrict__ Bu, const float* __restrict__ lamRe,
                             const float* __restrict__ lamIm, float* __restrict__ carRe,
                             float* __restrict__ carIm) {
    int b = blockIdx.x >> 7, c = blockIdx.x & (CHUNKS - 1);
    int n = threadIdx.x;
    float lr = lamRe[n], li = lamIm[n];
    float hr = 0.f, hi = 0.f;
    const unsigned* p = (const unsigned*)Bu + ((size_t)(b * SEQL + c * CHUNKLN)) * 256 + n;
    for (int i = 0; i < CHUNKLN; ++i) {
        unsigned u = *p;
        float br = __uint_as_float(u << 16);
        float bi = __uint_as_float(u & 0xffff0000u);
        float nr = lr * hr - li * hi + br;
        float ni = lr * hi + li * hr + bi;
        hr = nr; hi = ni; p += 256;
    }
    carRe[(size_t)blockIdx.x * 256 + n] = hr;
    carIm[(size_t)blockIdx.x * 256 + n] = hi;
}

__global__ void scan2_kernel(const float* __restrict__ carRe, const float* __restrict__ carIm,
                             const float* __restrict__ lamSRe, const float* __restrict__ lamSIm,
                             float* __restrict__ iniRe, float* __restrict__ iniIm) {
    int b = blockIdx.x, n = threadIdx.x;
    float lr = lamSRe[n], li = lamSIm[n];
    float hr = 0.f, hi = 0.f;
    for (int c = 0; c < CHUNKS; ++c) {
        size_t idx = ((size_t)b * CHUNKS + c) * 256 + n;
        iniRe[idx] = hr; iniIm[idx] = hi;
        float cr = carRe[idx], ci = carIm[idx];
        float nr = lr * hr - li * hi + cr;
        float ni = lr * hi + li * hr + ci;
        hr = nr; hi = ni;
    }
}

__global__ void scan3_kernel(bh* __restrict__ Bu, const float* __restrict__ lamRe,
                             const float* __restrict__ lamIm, const float* __restrict__ iniRe,
                             const float* __restrict__ iniIm, float* __restrict__ outTail,
                             int tailN) {
    int b = blockIdx.x >> 7, c = blockIdx.x & (CHUNKS - 1);
    int n = threadIdx.x;
    float lr = lamRe[n], li = lamIm[n];
    size_t idx = (size_t)blockIdx.x * 256 + n;
    float hr = iniRe[idx], hi = iniIm[idx];
    unsigned* p = (unsigned*)Bu + ((size_t)(b * SEQL + c * CHUNKLN)) * 256 + n;
    for (int i = 0; i < CHUNKLN; ++i) {
        unsigned u = *p;
        float br = __uint_as_float(u << 16);
        float bi = __uint_as_float(u & 0xffff0000u);
        float nr = lr * hr - li * hi + br;
        float ni = lr * hi + li * hr + bi;
        hr = nr; hi = ni;
        bh2 o; o[0] = (bh)hr; o[1] = (bh)hi;
        *(bh2*)p = o;
        p += 256;
    }
    if (c == CHUNKS - 1) {
        if (tailN >= 4096) {
            outTail[b * 256 + n]        = hr;
            outTail[2048 + b * 256 + n] = hi;
        } else {
            outTail[b * 256 + n] = hr;
        }
    }
}

// ---------------- launch ----------------
extern "C" void kernel_launch(void* const* d_in, const int* in_sizes, int n_in,
                              void* d_out, int out_size, void* d_ws, size_t ws_size,
                              hipStream_t stream) {
    const float* x        = (const float*)d_in[0];
    const float* W        = (const float*)d_in[1];
    const float* bvec     = (const float*)d_in[2];
    const float* nu_log   = (const float*)d_in[3];
    const float* theta_lg = (const float*)d_in[4];
    const float* gamma_lg = (const float*)d_in[5];
    const float* Bre      = (const float*)d_in[6];
    const float* Bim      = (const float*)d_in[7];
    const float* Cre      = (const float*)d_in[8];
    const float* Cim      = (const float*)d_in[9];
    const float* Dvec     = (const float*)d_in[10];

    char* ws = (char*)d_ws;
    bh* xh   = (bh*)(ws);                                   // 64 MB
    bh* bu   = (bh*)(ws + 67108864);                        // 64 MB (becomes h in-place)
    bh* wbt  = (bh*)(ws + 134217728);                       // 512 KB
    bh* wct  = (bh*)(ws + 134217728 + 524288);              // 1 MB
    float* Wt = (float*)(ws + 134217728 + 524288 + 1048576); // 1 MB
    float* sm = (float*)(ws + 134217728 + 524288 + 1048576 + 1048576);
    float* bB = sm;               // 512 (interleaved)
    float* bD = sm + 512;         // 512
    float* lamRe  = sm + 1024;    // 256
    float* lamIm  = sm + 1280;
    float* lamSRe = sm + 1536;
    float* lamSIm = sm + 1792;
    float* gamma  = sm + 2048;    // 256
    float* carRe  = sm + 2304;                 // 8*128*256 each
    float* carIm  = carRe + (size_t)BATCH * CHUNKS * 256;
    float* iniRe  = carIm + (size_t)BATCH * CHUNKS * 256;
    float* iniIm  = iniRe + (size_t)BATCH * CHUNKS * 256;

    float* outF    = (float*)d_out;
    float* outTail = outF + (size_t)MTOT * DOUTD;
    int tailN = out_size - MTOT * DOUTD;       // 4096 (float view) or 2048

    setup_kernel<<<16705, 256, 0, stream>>>((const float4*)x, xh, W, Wt,
                                            nu_log, theta_lg, gamma_lg, Bre, Bim, bvec, Dvec,
                                            lamRe, lamIm, lamSRe, lamSIm, gamma, bB, bD);
    prepBC_kernel<<<2176, 256, 0, stream>>>(Wt, Bre, Bim, gamma, wbt, Cre, Cim, Dvec, wct);

    gemm_kernel<512, false, false><<<512, 512, 0, stream>>>(xh, nullptr, wbt, bB, nullptr, bu);

    scan1_kernel<<<BATCH * CHUNKS, 256, 0, stream>>>(bu, lamRe, lamIm, carRe, carIm);
    scan2_kernel<<<BATCH, 256, 0, stream>>>(carRe, carIm, lamSRe, lamSIm, iniRe, iniIm);
    scan3_kernel<<<BATCH * CHUNKS, 256, 0, stream>>>(bu, lamRe, lamIm, iniRe, iniIm, outTail, tailN);

    gemm_kernel<1024, true, true><<<512, 512, 0, stream>>>(bu, xh, wct, bD, outF, nullptr);
}